// Round 9
// baseline (1538.816 us; speedup 1.0000x reference)
//
#include <hip/hip_runtime.h>
#include <cstdint>
#include <cstddef>

#define H 450
#define H2 900
#define KP 480
#define KP2 960
#define NMESS 10241
#define NNODE 5120
#define MPAD 10368                 // 162 * 64
#define PSZ ((size_t)MPAD * KP)    // plane size in shorts = 4,976,640
#define KM 5
#define KN 6
#define LDI 1350                   // CH row stride (c_z | c_h | r1b)

typedef __attribute__((ext_vector_type(8))) short short8;   // 8 bf16
typedef __attribute__((ext_vector_type(4))) float f32x4;

__device__ __forceinline__ short bf16rne(float f) {
  union { float f; unsigned u; } x; x.f = f;
  unsigned u = x.u;
  u += 0x7FFF + ((u >> 16) & 1);
  return (short)(u >> 16);
}
__device__ __forceinline__ float bf16tof(short s) {
  union { float f; unsigned u; } x;
  x.u = ((unsigned)(unsigned short)s) << 16;
  return x.f;
}
__device__ __forceinline__ void bf16split(float v, short& hi, short& lo) {
  hi = bf16rne(v);
  lo = bf16rne(v - bf16tof(hi));
}
__device__ __forceinline__ float sigmoidf_(float x) {
  return 1.f / (1.f + __expf(-x));
}

// direct global->LDS 16B DMA (LDS dest: wave-uniform base + lane*16)
__device__ __forceinline__ void gll16(const short* g, short* l) {
  __builtin_amdgcn_global_load_lds(
      (const __attribute__((address_space(1))) void*)g,
      (__attribute__((address_space(3))) void*)l, 16, 0, 0);
}

// ---------------- split-bf16 MFMA GEMM v7: 64x64 tiles, 2-deep pipeline ----
// 256 threads (4 waves, 32x32 wave tiles), BK=32, 48 KB LDS (3 bufs) ->
// 3 blocks/CU. Counted vmcnt: wait buf t+1 while buf t+2 stays in flight
// (never drain to 0 in steady state). Source-swizzled gload_lds staging,
// XCD-chunked block swizzle.
#define BM 64
#define BN 64
#define BK 32

struct SmemT { short As[3][64][64]; short Bs[3][64][64]; };   // 48 KB

__device__ __forceinline__ void xcd_swz(int gx, int gy, int& bm, int& bn) {
  const int nwg = gx * gy;
  int lid = blockIdx.y * gx + blockIdx.x;
  const int q = nwg >> 3, r = nwg & 7;
  const int xcd = lid & 7, seq = lid >> 3;
  int sid = (xcd < r) ? (xcd * (q + 1) + seq)
                      : (r * (q + 1) + (xcd - r) * q + seq);
  bm = (sid / gx) * BM;
  bn = (sid % gx) * BN;
}

// OUT: 0 = f32 C (+bias, opt relu)   1 = split bf16 planes (ldc in shorts)
template<int ACT, int OUT>
__device__ __forceinline__ void gemm_core(
    SmemT& sm, const short* __restrict__ Ah, const short* __restrict__ Al,
    int Kpad, const short* __restrict__ Bth, const short* __restrict__ Btl,
    const float* __restrict__ bias,
    float* C, int ldc, short* Ch, short* Cl,
    int M, int N, int bm, int bn)
{
  const int tid  = threadIdx.x;
  const int lane = tid & 63;
  const int wid  = tid >> 6;          // 0..3
  const int wm   = (wid >> 1) * 32;
  const int wn   = (wid & 1) * 32;
  const int l15  = lane & 15;
  const int s8   = (lane >> 4) * 8;   // k sub-offset in halves
  const int rr0  = (lane >> 4) * 4;

  // staging: unified 128 rows (0-63 = A, 64-127 = B); wave wid -> rows 32w..32w+31
  const int lr = lane >> 3;
  const int sl = lane & 7;
  const int t0 = sl ^ lr;             // data slot fetched by this lane
  const short* src[4];
#pragma unroll
  for (int qq = 0; qq < 4; ++qq) {
    const int rrow = wid * 32 + qq * 8 + lr;
    const bool isA = rrow < 64;
    const int grow = isA ? (bm + rrow) : (bn + rrow - 64);
    const short* pl = isA ? (t0 < 4 ? Ah : Al) : (t0 < 4 ? Bth : Btl);
    src[qq] = pl + (size_t)grow * Kpad + (t0 & 3) * 8;
  }
  const int nk = Kpad / BK;

  f32x4 acc[2][2];
#pragma unroll
  for (int i = 0; i < 2; ++i)
#pragma unroll
    for (int j = 0; j < 2; ++j)
#pragma unroll
      for (int t = 0; t < 4; ++t) acc[i][j][t] = 0.f;

  auto STAGE = [&](int b, int koff) {   // 4 vmem-lds loads per wave
#pragma unroll
    for (int qq = 0; qq < 4; ++qq) {
      const int r0 = wid * 32 + qq * 8;
      short* d = (r0 < 64) ? &sm.As[b][r0][0] : &sm.Bs[b][r0 - 64][0];
      gll16(src[qq] + koff, d);
    }
  };

  // prologue: 2 stages in flight, wait only the first
  STAGE(0, 0);
  STAGE(1, BK);                       // nk >= 2 always (K >= 64)
  __builtin_amdgcn_sched_barrier(0);
  asm volatile("s_waitcnt vmcnt(4)" ::: "memory");
  __builtin_amdgcn_s_barrier();

  int cur = 0;
  for (int t = 0; t < nk; ++t) {
    if (t + 2 < nk) STAGE((t + 2) % 3, (t + 2) * BK);

    short8 ah[2], al[2], bh[2], bl[2];
#pragma unroll
    for (int i = 0; i < 2; ++i) {
      const int rA = wm + i*16 + l15;
      const int xr = (rA & 7) << 3;
      ah[i] = *(const short8*)&sm.As[cur][rA][(s8)      ^ xr];
      al[i] = *(const short8*)&sm.As[cur][rA][(s8 + 32) ^ xr];
    }
#pragma unroll
    for (int j = 0; j < 2; ++j) {
      const int rB = wn + j*16 + l15;
      const int xr = (rB & 7) << 3;
      bh[j] = *(const short8*)&sm.Bs[cur][rB][(s8)      ^ xr];
      bl[j] = *(const short8*)&sm.Bs[cur][rB][(s8 + 32) ^ xr];
    }
    __builtin_amdgcn_s_setprio(1);
#pragma unroll
    for (int j = 0; j < 2; ++j)
#pragma unroll
      for (int i = 0; i < 2; ++i) {
        acc[i][j] = __builtin_amdgcn_mfma_f32_16x16x32_bf16(ah[i], bh[j], acc[i][j], 0, 0, 0);
        acc[i][j] = __builtin_amdgcn_mfma_f32_16x16x32_bf16(al[i], bh[j], acc[i][j], 0, 0, 0);
        acc[i][j] = __builtin_amdgcn_mfma_f32_16x16x32_bf16(ah[i], bl[j], acc[i][j], 0, 0, 0);
      }
    __builtin_amdgcn_s_setprio(0);
    __builtin_amdgcn_sched_barrier(0);
    // buf t+1 must be resident for next iter; buf t+2 (4 loads) stays in flight
    if (t + 2 < nk) asm volatile("s_waitcnt vmcnt(4)" ::: "memory");
    else            asm volatile("s_waitcnt vmcnt(0)" ::: "memory");
    __builtin_amdgcn_s_barrier();
    __builtin_amdgcn_sched_barrier(0);
    cur = (cur == 2) ? 0 : cur + 1;
  }

#pragma unroll
  for (int j = 0; j < 2; ++j) {
    int col = bn + wn + j*16 + l15;
    if (col >= N) continue;
    float bv = (OUT == 0 && bias) ? bias[col] : 0.f;
#pragma unroll
    for (int i = 0; i < 2; ++i) {
      int row0 = bm + wm + i*16 + rr0;
#pragma unroll
      for (int rr = 0; rr < 4; ++rr) {
        int row = row0 + rr;
        if (row >= M) continue;
        float v = acc[i][j][rr] + bv;
        if (OUT == 0) {
          if (ACT == 1) v = fmaxf(v, 0.f);
          C[(size_t)row * ldc + col] = v;
        } else {
          short hi, lo; bf16split(v, hi, lo);
          Ch[(size_t)row * ldc + col] = hi;
          Cl[(size_t)row * ldc + col] = lo;
        }
      }
    }
  }
}

template<int ACT>
__global__ __launch_bounds__(256, 3)
void gemm4(const short* __restrict__ Ah, const short* __restrict__ Al, int Kpad,
           const short* __restrict__ Bth, const short* __restrict__ Btl,
           const float* __restrict__ bias,
           float* C, int ldc, int M, int N)
{
  __shared__ SmemT sm;
  int bm, bn; xcd_swz(gridDim.x, gridDim.y, bm, bn);
  gemm_core<ACT, 0>(sm, Ah, Al, Kpad, Bth, Btl, bias, C, ldc, nullptr, nullptr, M, N, bm, bn);
}

// grouped: z=0: t_h = ghS@WhB -> g (f32); z=1: t_z = shS@WzB -> h planes (split)
__global__ __launch_bounds__(256, 3)
void gemm4_pair(const short* __restrict__ A0h, const short* __restrict__ A0l,
                const short* __restrict__ B0h, const short* __restrict__ B0l,
                float* C0,
                const short* __restrict__ A1h, const short* __restrict__ A1l,
                const short* __restrict__ B1h, const short* __restrict__ B1l,
                short* C1h, short* C1l)
{
  __shared__ SmemT sm;
  int bm, bn; xcd_swz(gridDim.x, gridDim.y, bm, bn);
  if (blockIdx.z == 0)
    gemm_core<0, 0>(sm, A0h, A0l, KP, B0h, B0l, nullptr, C0, H, nullptr, nullptr, NMESS, H, bm, bn);
  else
    gemm_core<0, 1>(sm, A1h, A1l, KP, B1h, B1l, nullptr, nullptr, KP, C1h, C1l, NMESS, H, bm, bn);
}

// ---------------- weight transpose + bf16 hi/lo split ----------------
__global__ __launch_bounds__(256)
void k_wT(const float* __restrict__ W, int Kreal,
          short* __restrict__ Bth, short* __restrict__ Btl, int Kpad, int rmax) {
  __shared__ float T[32][33];
  const int tx = threadIdx.x & 31;
  const int ty = threadIdx.x >> 5;
  const int k0 = blockIdx.x * 32;
  const int c0 = blockIdx.y * 32;
#pragma unroll
  for (int i = 0; i < 4; ++i) {
    int k = k0 + ty + i*8, c = c0 + tx;
    T[ty + i*8][tx] = (k < Kreal && c < H) ? W[(size_t)k * H + c] : 0.f;
  }
  __syncthreads();
#pragma unroll
  for (int i = 0; i < 4; ++i) {
    int c = c0 + ty + i*8, k = k0 + tx;
    if (k < Kpad && c < rmax) {
      short hi, lo;
      bf16split(T[tx][ty + i*8], hi, lo);
      Bth[(size_t)c * Kpad + k] = hi;
      Btl[(size_t)c * Kpad + k] = lo;
    }
  }
}

__global__ void k_biascat(const float* __restrict__ bz, const float* __restrict__ bh,
                          const float* __restrict__ bu, float* __restrict__ biasI) {
  int c = blockIdx.x * blockDim.x + threadIdx.x;
  if (c >= 1408) return;
  float v = 0.f;
  if (c < 450) v = bz[c];
  else if (c < 900) v = bh[c - 450];
  else if (c < 1350) v = bu[c - 900];
  biasI[c] = v;
}

// ---------------- elementwise / gather kernels ----------------

__global__ void k_build_idx(const int* __restrict__ fnode,
                            const int* __restrict__ fmess,
                            int* __restrict__ idxM) {
  int m = blockIdx.x * blockDim.x + threadIdx.x;
  if (m < NMESS) idxM[m] = fnode[fmess[m]];
}

__global__ void k_embsplit(const float* __restrict__ emb,
                           const int* __restrict__ idxM,
                           short* __restrict__ eh, short* __restrict__ el) {
  int m = blockIdx.x, j = threadIdx.x * 2;
  if (j >= H) return;
  float2 v = *(const float2*)&emb[(size_t)idxM[m] * H + j];
  short2 h2, l2;
  bf16split(v.x, h2.x, l2.x); bf16split(v.y, h2.y, l2.y);
  size_t o = (size_t)m * KP + j;
  *(short2*)&eh[o] = h2; *(short2*)&el[o] = l2;
}

// one pass over neighbors: sum_h planes + sum_gh planes
__global__ void k_gather2(const short* __restrict__ hh, const short* __restrict__ hl,
                          const float* __restrict__ g,
                          const float* __restrict__ CHp,   // r1b at +900, stride LDI
                          const int* __restrict__ mg,
                          short* __restrict__ shh, short* __restrict__ shl,
                          short* __restrict__ ghh, short* __restrict__ ghl) {
  int m = blockIdx.x, j = threadIdx.x * 2;
  if (j >= H) return;
  const int* e = mg + (size_t)m * KM;
  float2 rb = *(const float2*)&CHp[(size_t)m * LDI + 900 + j];
  float s0 = 0.f, s1 = 0.f, t0 = 0.f, t1 = 0.f;
#pragma unroll
  for (int k = 0; k < KM; ++k) {
    int ek = e[k];
    size_t oP = (size_t)ek * KP + j;
    float2 gv = *(const float2*)&g[(size_t)ek * H + j];
    short2 ph = *(const short2*)&hh[oP];
    short2 pl = *(const short2*)&hl[oP];
    float h0 = bf16tof(ph.x) + bf16tof(pl.x);
    float h1 = bf16tof(ph.y) + bf16tof(pl.y);
    s0 += h0;                          s1 += h1;
    t0 += sigmoidf_(rb.x + gv.x) * h0; t1 += sigmoidf_(rb.y + gv.y) * h1;
  }
  size_t o = (size_t)m * KP + j;
  short2 h2, l2;
  bf16split(s0, h2.x, l2.x); bf16split(s1, h2.y, l2.y);
  *(short2*)&shh[o] = h2; *(short2*)&shl[o] = l2;
  bf16split(t0, h2.x, l2.x); bf16split(t1, h2.y, l2.y);
  *(short2*)&ghh[o] = h2; *(short2*)&ghl[o] = l2;
}

// h = mask*((1-z)*sum_h + z*tanh(c_h+th)); tz read from h planes, overwritten in place
__global__ void k_combine(const float* __restrict__ CHp,
                          const float* __restrict__ th,
                          const short* __restrict__ shh, const short* __restrict__ shl,
                          short* hh, short* hl) {
  int m = blockIdx.x, j = threadIdx.x * 2;
  if (j >= H) return;
  size_t oc = (size_t)m * LDI + j;
  size_t op = (size_t)m * KP + j;
  size_t og = (size_t)m * H + j;
  float2 cz = *(const float2*)&CHp[oc];
  float2 ch = *(const float2*)&CHp[oc + 450];
  float2 tv = *(const float2*)&th[og];
  short2 tzh = *(const short2*)&hh[op];
  short2 tzl = *(const short2*)&hl[op];
  short2 smh = *(const short2*)&shh[op];
  short2 sml = *(const short2*)&shl[op];
  float tz0 = bf16tof(tzh.x) + bf16tof(tzl.x);
  float tz1 = bf16tof(tzh.y) + bf16tof(tzl.y);
  float sm0 = bf16tof(smh.x) + bf16tof(sml.x);
  float sm1 = bf16tof(smh.y) + bf16tof(sml.y);
  float z0 = sigmoidf_(cz.x + tz0);
  float z1 = sigmoidf_(cz.y + tz1);
  float p0 = tanhf(ch.x + tv.x);
  float p1 = tanhf(ch.y + tv.y);
  float v0 = (1.f - z0) * sm0 + z0 * p0;
  float v1 = (1.f - z1) * sm1 + z1 * p1;
  if (m == 0) { v0 = 0.f; v1 = 0.f; }
  short2 h2, l2;
  bf16split(v0, h2.x, l2.x); bf16split(v1, h2.y, l2.y);
  *(short2*)&hh[op] = h2; *(short2*)&hl[op] = l2;
}

// Acat planes [n][960] = [split(emb[fnode[n]]), split(sum_k h[ng[n,k]]), 0-pad]
__global__ void k_nodecat(const float* __restrict__ emb,
                          const int* __restrict__ fnode,
                          const short* __restrict__ hh, const short* __restrict__ hl,
                          const int* __restrict__ ng,
                          short* __restrict__ Ah, short* __restrict__ Al) {
  int n = blockIdx.x, t = threadIdx.x, j = t * 2;
  if (j < H) {
    float2 v = *(const float2*)&emb[(size_t)fnode[n] * H + j];
    short2 h2, l2;
    bf16split(v.x, h2.x, l2.x); bf16split(v.y, h2.y, l2.y);
    size_t o = (size_t)n * KP2 + j;
    *(short2*)&Ah[o] = h2; *(short2*)&Al[o] = l2;

    const int* e = ng + (size_t)n * KN;
    float s0 = 0.f, s1 = 0.f;
#pragma unroll
    for (int k = 0; k < KN; ++k) {
      size_t oP = (size_t)e[k] * KP + j;
      short2 ph = *(const short2*)&hh[oP];
      short2 pl = *(const short2*)&hl[oP];
      s0 += bf16tof(ph.x) + bf16tof(pl.x);
      s1 += bf16tof(ph.y) + bf16tof(pl.y);
    }
    bf16split(s0, h2.x, l2.x); bf16split(s1, h2.y, l2.y);
    o = (size_t)n * KP2 + H + j;
    *(short2*)&Ah[o] = h2; *(short2*)&Al[o] = l2;
  }
  if (t < 30) {   // zero cols [900,960)
    short2 z2; z2.x = 0; z2.y = 0;
    size_t o = (size_t)n * KP2 + H2 + t * 2;
    *(short2*)&Ah[o] = z2; *(short2*)&Al[o] = z2;
  }
}

// ---------------- launch ----------------

extern "C" void kernel_launch(void* const* d_in, const int* in_sizes, int n_in,
                              void* d_out, int out_size, void* d_ws, size_t ws_size,
                              hipStream_t stream) {
  (void)in_sizes; (void)n_in; (void)out_size; (void)ws_size;

  const int*   fnode      = (const int*)d_in[0];
  const int*   fmess      = (const int*)d_in[1];
  const int*   node_graph = (const int*)d_in[2];
  const int*   mess_graph = (const int*)d_in[3];
  const float* emb        = (const float*)d_in[4];
  const float* Wz         = (const float*)d_in[5];
  const float* bz         = (const float*)d_in[6];
  const float* Wr         = (const float*)d_in[7];
  const float* Ur         = (const float*)d_in[8];
  const float* bu         = (const float*)d_in[9];
  const float* Wh         = (const float*)d_in[10];
  const float* bh         = (const float*)d_in[11];
  const float* Wo         = (const float*)d_in[12];
  const float* bo         = (const float*)d_in[13];

  // ---- workspace (123.5 MB, proven budget) ----
  float* CH  = (float*)d_ws;                       // [M][1350]: c_z|c_h|r1b
  float* g   = CH + (size_t)NMESS * LDI;           // [M][450]: Ur out, then t_h
  short* P   = (short*)(g + (size_t)NMESS * H);
  short* hSh  = P;
  short* hSl  = P + 1 * PSZ;
  short* shSh = P + 2 * PSZ;     // sum_h hi (later Acat hi, stride 960)
  short* shSl = P + 3 * PSZ;
  short* ghSh = P + 4 * PSZ;     // sum_gh hi (also fmess_e hi)

  // ---- d_out messages region (17.6 of 18.4 MB) ----
  char*  scr   = (char*)d_out + (size_t)NNODE * H * 4;
  int*   idxM  = (int*)scr;                          // 40,964 B
  float* biasI = (float*)(scr + 40976);              // 1408 f32
  short* BtIh  = (short*)(scr + 46608);              // [1408][480]
  short* BtIl  = BtIh  + (size_t)1408 * KP;
  short* BtUrh = BtIl  + (size_t)1408 * KP;          // [512][480] each below
  short* BtUrl = BtUrh + (size_t)512 * KP;
  short* BtZh  = BtUrl + (size_t)512 * KP;           // Wz bottom
  short* BtZl  = BtZh  + (size_t)512 * KP;
  short* BtHh  = BtZl  + (size_t)512 * KP;           // Wh bottom
  short* BtHl  = BtHh  + (size_t)512 * KP;
  short* BtOh  = BtHl  + (size_t)512 * KP;           // Wo [512][960]
  short* BtOl  = BtOh  + (size_t)512 * KP2;
  short* ghSl  = BtOl  + (size_t)512 * KP2;          // sum_gh lo plane

  // zero planes (pads must be 0 / h0 = 0) + scratch region
  hipMemsetAsync(P, 0, 5 * PSZ * sizeof(short), stream);
  hipMemsetAsync(scr, 0, (size_t)NMESS * H * sizeof(float), stream);

  k_build_idx<<<(NMESS + 255) / 256, 256, 0, stream>>>(fnode, fmess, idxM);

  // weight prep: merged invariant [Wz_t | Wh_t | Wr] rows 0/450/900, then GRU/out mats
  dim3 gT(KP / 32, 16), gT2(KP2 / 32, 16);
  k_wT<<<gT,  256, 0, stream>>>(Wz,                  H, BtIh,            BtIl,            KP, 512);
  k_wT<<<gT,  256, 0, stream>>>(Wh,                  H, BtIh + 450 * KP, BtIl + 450 * KP, KP, 512);
  k_wT<<<gT,  256, 0, stream>>>(Wr,                  H, BtIh + 900 * KP, BtIl + 900 * KP, KP, 508);
  k_wT<<<gT,  256, 0, stream>>>(Ur,                  H, BtUrh, BtUrl, KP, 512);
  k_wT<<<gT,  256, 0, stream>>>(Wz + (size_t)H * H,  H, BtZh,  BtZl,  KP, 512);
  k_wT<<<gT,  256, 0, stream>>>(Wh + (size_t)H * H,  H, BtHh,  BtHl,  KP, 512);
  k_wT<<<gT2, 256, 0, stream>>>(Wo,                 H2, BtOh,  BtOl,  KP2, 512);
  k_biascat<<<6, 256, 0, stream>>>(bz, bh, bu, biasI);

  // fmess_e split into ghS pair
  k_embsplit<<<NMESS, 256, 0, stream>>>(emb, idxM, ghSh, ghSl);

  // merged invariant GEMM: CH = fmess_e @ [WzT|WhT|Wr] + [bz|bh|bu]
  dim3 gI(22, MPAD / BM);          // (22, 162)
  gemm4<0><<<gI, 256, 0, stream>>>(ghSh, ghSl, KP, BtIh, BtIl, biasI, CH, LDI, NMESS, LDI);

  dim3 gB(8, MPAD / BM);           // (8, 162)
  dim3 gP(8, MPAD / BM, 2);        // grouped t_h + t_z
  for (int d = 0; d < 8; ++d) {
    // g = h @ Ur
    gemm4<0><<<gB, 256, 0, stream>>>(hSh, hSl, KP, BtUrh, BtUrl, nullptr, g, H, NMESS, H);
    // sum_h & sum_gh planes in one pass
    k_gather2<<<NMESS, 256, 0, stream>>>(hSh, hSl, g, CH, mess_graph, shSh, shSl, ghSh, ghSl);
    // t_h = ghS@WhB -> g (dead)  ||  t_z = shS@WzB -> h planes (old h dead)
    gemm4_pair<<<gP, 256, 0, stream>>>(ghSh, ghSl, BtHh, BtHl, g,
                                       shSh, shSl, BtZh, BtZl, hSh, hSl);
    // combine in place (tz in h planes -> h)
    k_combine<<<NMESS, 256, 0, stream>>>(CH, g, shSh, shSl, hSh, hSl);
  }

  // Acat planes (stride 960) then output GEMM with relu
  k_nodecat<<<NNODE, 256, 0, stream>>>(emb, fnode, hSh, hSl, node_graph, shSh, shSl);
  dim3 gF(8, NNODE / BM);          // (8, 80)
  gemm4<1><<<gF, 256, 0, stream>>>(shSh, shSl, KP2, BtOh, BtOl, bo, (float*)d_out, H, NNODE, H);

  // messages output = zeros (wipes idx + weights + ghSl) — AFTER final GEMM
  hipMemsetAsync((float*)d_out + (size_t)NNODE * H, 0, (size_t)NMESS * H * sizeof(float), stream);
}

// Round 10
// 1044.057 us; speedup vs baseline: 1.4739x; 1.4739x over previous
//
#include <hip/hip_runtime.h>
#include <cstdint>
#include <cstddef>

#define H 450
#define H2 900
#define KP 480
#define KP2 960
#define NMESS 10241
#define NNODE 5120
#define MPAD 10368                 // 162 * 64
#define SPP1 960                   // packed row stride (shorts) for Kpad=480
#define SPP2 1920                  // for Kpad=960
#define PPSZ ((size_t)MPAD * SPP1) // packed plane size in shorts
#define KM 5
#define KN 6
#define LDCH 912                   // CH row stride (f32), 64B-aligned

typedef __attribute__((ext_vector_type(8))) short short8;   // 8 bf16
typedef __attribute__((ext_vector_type(4))) float f32x4;

__device__ __forceinline__ short bf16rne(float f) {
  union { float f; unsigned u; } x; x.f = f;
  unsigned u = x.u;
  u += 0x7FFF + ((u >> 16) & 1);
  return (short)(u >> 16);
}
__device__ __forceinline__ float bf16tof(short s) {
  union { float f; unsigned u; } x;
  x.u = ((unsigned)(unsigned short)s) << 16;
  return x.f;
}
__device__ __forceinline__ void bf16split(float v, short& hi, short& lo) {
  hi = bf16rne(v);
  lo = bf16rne(v - bf16tof(hi));
}
__device__ __forceinline__ float sigmoidf_(float x) {
  return 1.f / (1.f + __expf(-x));
}

// packed element offset: hi at PPIX, lo at PPIX+32
__device__ __forceinline__ size_t ppix(int row, int k, int spp) {
  return (size_t)row * spp + ((k >> 5) << 6) + (k & 31);
}

// direct global->LDS 16B DMA (LDS dest: wave-uniform base + lane*16)
__device__ __forceinline__ void gll16(const short* g, short* l) {
  __builtin_amdgcn_global_load_lds(
      (const __attribute__((address_space(1))) void*)g,
      (__attribute__((address_space(3))) void*)l, 16, 0, 0);
}

// ---------------- split-bf16 MFMA GEMM v8: packed planes ----------------
// A,B packed [row][k-chunk][hi*32|lo*32] bf16. 256 thr (4 waves, 32x32 wave
// tiles), BK=32, 2-buf 32 KB LDS -> 5 blocks/CU. gload_lds staging: one
// contiguous 128B run per row per chunk; source slot = (lane&7)^(row&7),
// read-side XOR matches. XCD-chunked block swizzle.
#define BM 64
#define BN 64
#define BK 32

struct SmemT { short As[2][64][64]; short Bs[2][64][64]; };   // 32 KB

__device__ __forceinline__ void xcd_swz(int gx, int gy, int& bm, int& bn) {
  const int nwg = gx * gy;
  int lid = blockIdx.y * gx + blockIdx.x;
  const int q = nwg >> 3, r = nwg & 7;
  const int xcd = lid & 7, seq = lid >> 3;
  int sid = (xcd < r) ? (xcd * (q + 1) + seq)
                      : (r * (q + 1) + (xcd - r) * q + seq);
  bm = (sid / gx) * BM;
  bn = (sid % gx) * BN;
}

// OUT: 0 = f32 C (+bias, opt relu)
//      1 = packed split bf16 planes (Cs, stride SPP1)
//      3 = single bf16 (Cs, stride 480), +bias
template<int ACT, int OUT>
__device__ __forceinline__ void gemm_core(
    SmemT& sm, const short* __restrict__ Apk, int Kpad,
    const short* __restrict__ Bpk,
    const float* __restrict__ bias,
    float* C, int ldc, short* Cs,
    int M, int N, int bm, int bn)
{
  const int tid  = threadIdx.x;
  const int lane = tid & 63;
  const int wid  = tid >> 6;          // 0..3
  const int wm   = (wid >> 1) * 32;
  const int wn   = (wid & 1) * 32;
  const int l15  = lane & 15;
  const int s8   = (lane >> 4) * 8;   // k sub-offset in halves
  const int rr0  = (lane >> 4) * 4;
  const int spp  = Kpad * 2;

  // staging: unified 128 rows (0-63 = A, 64-127 = B); wave wid -> rows 32w..32w+31
  const int lr = lane >> 3;
  const int sl = lane & 7;
  const int t0 = sl ^ lr;             // packed slot (0-3 hi, 4-7 lo)
  const short* src[4];
#pragma unroll
  for (int qq = 0; qq < 4; ++qq) {
    const int rrow = wid * 32 + qq * 8 + lr;
    const bool isA = rrow < 64;
    const int grow = isA ? (bm + rrow) : (bn + rrow - 64);
    src[qq] = (isA ? Apk : Bpk) + (size_t)grow * spp + t0 * 8;
  }
  const int nk = Kpad / BK;

  f32x4 acc[2][2];
#pragma unroll
  for (int i = 0; i < 2; ++i)
#pragma unroll
    for (int j = 0; j < 2; ++j)
#pragma unroll
      for (int t = 0; t < 4; ++t) acc[i][j][t] = 0.f;

  auto STAGE = [&](int b, int koff) {
#pragma unroll
    for (int qq = 0; qq < 4; ++qq) {
      const int r0 = wid * 32 + qq * 8;
      short* d = (r0 < 64) ? &sm.As[b][r0][0] : &sm.Bs[b][r0 - 64][0];
      gll16(src[qq] + koff, d);
    }
  };

  STAGE(0, 0);
  __syncthreads();
  int cur = 0;
  for (int t = 0; t < nk; ++t) {
    if (t + 1 < nk) STAGE(cur ^ 1, (t + 1) * 64);
    short8 ah[2], al[2], bh[2], bl[2];
#pragma unroll
    for (int i = 0; i < 2; ++i) {
      const int rA = wm + i*16 + l15;
      const int xr = (rA & 7) << 3;
      ah[i] = *(const short8*)&sm.As[cur][rA][(s8)      ^ xr];
      al[i] = *(const short8*)&sm.As[cur][rA][(s8 + 32) ^ xr];
    }
#pragma unroll
    for (int j = 0; j < 2; ++j) {
      const int rB = wn + j*16 + l15;
      const int xr = (rB & 7) << 3;
      bh[j] = *(const short8*)&sm.Bs[cur][rB][(s8)      ^ xr];
      bl[j] = *(const short8*)&sm.Bs[cur][rB][(s8 + 32) ^ xr];
    }
    __builtin_amdgcn_s_setprio(1);
#pragma unroll
    for (int j = 0; j < 2; ++j)
#pragma unroll
      for (int i = 0; i < 2; ++i) {
        acc[i][j] = __builtin_amdgcn_mfma_f32_16x16x32_bf16(ah[i], bh[j], acc[i][j], 0, 0, 0);
        acc[i][j] = __builtin_amdgcn_mfma_f32_16x16x32_bf16(al[i], bh[j], acc[i][j], 0, 0, 0);
        acc[i][j] = __builtin_amdgcn_mfma_f32_16x16x32_bf16(ah[i], bl[j], acc[i][j], 0, 0, 0);
      }
    __builtin_amdgcn_s_setprio(0);
    __syncthreads();   // drains next-tile gload_lds + read/write order
    cur ^= 1;
  }

#pragma unroll
  for (int j = 0; j < 2; ++j) {
    int col = bn + wn + j*16 + l15;
    if (col >= N) continue;
    float bv = ((OUT == 0 || OUT == 3) && bias) ? bias[col] : 0.f;
#pragma unroll
    for (int i = 0; i < 2; ++i) {
      int row0 = bm + wm + i*16 + rr0;
#pragma unroll
      for (int rr = 0; rr < 4; ++rr) {
        int row = row0 + rr;
        if (row >= M) continue;
        float v = acc[i][j][rr] + bv;
        if (OUT == 0) {
          if (ACT == 1) v = fmaxf(v, 0.f);
          C[(size_t)row * ldc + col] = v;
        } else if (OUT == 1) {
          short hi, lo; bf16split(v, hi, lo);
          size_t o = ppix(row, col, SPP1);
          Cs[o] = hi; Cs[o + 32] = lo;
        } else {  // OUT == 3: single bf16, stride 480
          Cs[(size_t)row * 480 + col] = bf16rne(v);
        }
      }
    }
  }
}

template<int ACT>
__global__ __launch_bounds__(256, 5)
void gemm4(const short* __restrict__ Apk, int Kpad,
           const short* __restrict__ Bpk,
           const float* __restrict__ bias,
           float* C, int ldc, int M, int N)
{
  __shared__ SmemT sm;
  int bm, bn; xcd_swz(gridDim.x, gridDim.y, bm, bn);
  gemm_core<ACT, 0>(sm, Apk, Kpad, Bpk, bias, C, ldc, nullptr, M, N, bm, bn);
}

// single-bf16 output GEMM (r1b)
__global__ __launch_bounds__(256, 5)
void gemm4_r(const short* __restrict__ Apk,
             const short* __restrict__ Bpk,
             const float* __restrict__ bias,
             short* Cs, int M, int N)
{
  __shared__ SmemT sm;
  int bm, bn; xcd_swz(gridDim.x, gridDim.y, bm, bn);
  gemm_core<0, 3>(sm, Apk, KP, Bpk, bias, nullptr, 0, Cs, M, N, bm, bn);
}

// grouped: z=0: t_h = ghP@WhB -> g (f32); z=1: t_z = shP@WzB -> hP (packed)
__global__ __launch_bounds__(256, 5)
void gemm4_pair(const short* __restrict__ A0, const short* __restrict__ B0,
                float* C0,
                const short* __restrict__ A1, const short* __restrict__ B1,
                short* C1)
{
  __shared__ SmemT sm;
  int bm, bn; xcd_swz(gridDim.x, gridDim.y, bm, bn);
  if (blockIdx.z == 0)
    gemm_core<0, 0>(sm, A0, KP, B0, nullptr, C0, H, nullptr, NMESS, H, bm, bn);
  else
    gemm_core<0, 1>(sm, A1, KP, B1, nullptr, nullptr, 0, C1, NMESS, H, bm, bn);
}

// ---------------- weight transpose + packed bf16 hi/lo split ----------------
// Bt packed [c][chunk][hi|lo], c = column of original W; c < rmax written
__global__ __launch_bounds__(256)
void k_wT(const float* __restrict__ W, int Kreal,
          short* __restrict__ Bt, int Kpad, int rmax) {
  __shared__ float T[32][33];
  const int tx = threadIdx.x & 31;
  const int ty = threadIdx.x >> 5;
  const int k0 = blockIdx.x * 32;
  const int c0 = blockIdx.y * 32;
  const int spp = Kpad * 2;
#pragma unroll
  for (int i = 0; i < 4; ++i) {
    int k = k0 + ty + i*8, c = c0 + tx;
    T[ty + i*8][tx] = (k < Kreal && c < H) ? W[(size_t)k * H + c] : 0.f;
  }
  __syncthreads();
#pragma unroll
  for (int i = 0; i < 4; ++i) {
    int c = c0 + ty + i*8, k = k0 + tx;
    if (k < Kpad && c < rmax) {
      short hi, lo;
      bf16split(T[tx][ty + i*8], hi, lo);
      size_t o = ppix(c, k, spp);
      Bt[o] = hi; Bt[o + 32] = lo;
    }
  }
}

__global__ void k_biascat(const float* __restrict__ bz, const float* __restrict__ bh,
                          float* __restrict__ biasI) {
  int c = blockIdx.x * blockDim.x + threadIdx.x;
  if (c >= LDCH) return;
  float v = 0.f;
  if (c < 450) v = bz[c];
  else if (c < 900) v = bh[c - 450];
  biasI[c] = v;
}

// ---------------- elementwise / gather kernels ----------------

__global__ void k_build_idx(const int* __restrict__ fnode,
                            const int* __restrict__ fmess,
                            int* __restrict__ idxM) {
  int m = blockIdx.x * blockDim.x + threadIdx.x;
  if (m < NMESS) idxM[m] = fnode[fmess[m]];
}

__global__ void k_embsplit(const float* __restrict__ emb,
                           const int* __restrict__ idxM,
                           short* __restrict__ eP) {
  int m = blockIdx.x, j = threadIdx.x * 2;
  if (j >= H) return;
  float2 v = *(const float2*)&emb[(size_t)idxM[m] * H + j];
  short2 h2, l2;
  bf16split(v.x, h2.x, l2.x); bf16split(v.y, h2.y, l2.y);
  size_t o = ppix(m, j, SPP1);
  *(short2*)&eP[o] = h2; *(short2*)&eP[o + 32] = l2;
}

// one pass over neighbors: sum_h + sum_gh packed planes
__global__ void k_gather2(const short* __restrict__ hP,
                          const float* __restrict__ g,
                          const short* __restrict__ r1b,   // [M][480] bf16
                          const int* __restrict__ mg,
                          short* __restrict__ shP, short* __restrict__ ghP) {
  int m = blockIdx.x, j = threadIdx.x * 2;
  if (j >= H) return;
  const int* e = mg + (size_t)m * KM;
  short2 rb2 = *(const short2*)&r1b[(size_t)m * 480 + j];
  float rb0 = bf16tof(rb2.x), rb1 = bf16tof(rb2.y);
  float s0 = 0.f, s1 = 0.f, t0 = 0.f, t1 = 0.f;
#pragma unroll
  for (int k = 0; k < KM; ++k) {
    int ek = e[k];
    size_t oP = ppix(ek, j, SPP1);
    float2 gv = *(const float2*)&g[(size_t)ek * H + j];
    short2 ph = *(const short2*)&hP[oP];
    short2 pl = *(const short2*)&hP[oP + 32];
    float h0 = bf16tof(ph.x) + bf16tof(pl.x);
    float h1 = bf16tof(ph.y) + bf16tof(pl.y);
    s0 += h0;                          s1 += h1;
    t0 += sigmoidf_(rb0 + gv.x) * h0;  t1 += sigmoidf_(rb1 + gv.y) * h1;
  }
  size_t o = ppix(m, j, SPP1);
  short2 h2, l2;
  bf16split(s0, h2.x, l2.x); bf16split(s1, h2.y, l2.y);
  *(short2*)&shP[o] = h2; *(short2*)&shP[o + 32] = l2;
  bf16split(t0, h2.x, l2.x); bf16split(t1, h2.y, l2.y);
  *(short2*)&ghP[o] = h2; *(short2*)&ghP[o + 32] = l2;
}

// h = mask*((1-z)*sum_h + z*tanh(c_h+th)); tz read from hP, overwritten in place
__global__ void k_combine(const float* __restrict__ CHp,   // [M][912]: c_z|c_h
                          const float* __restrict__ th,    // [M][450] t_h
                          const short* __restrict__ shP,
                          short* hP) {
  int m = blockIdx.x, j = threadIdx.x * 2;
  if (j >= H) return;
  size_t oc = (size_t)m * LDCH + j;
  size_t oP = ppix(m, j, SPP1);
  size_t og = (size_t)m * H + j;
  float2 cz = *(const float2*)&CHp[oc];
  float2 ch = *(const float2*)&CHp[oc + 450];
  float2 tv = *(const float2*)&th[og];
  short2 tzh = *(const short2*)&hP[oP];
  short2 tzl = *(const short2*)&hP[oP + 32];
  short2 smh = *(const short2*)&shP[oP];
  short2 sml = *(const short2*)&shP[oP + 32];
  float tz0 = bf16tof(tzh.x) + bf16tof(tzl.x);
  float tz1 = bf16tof(tzh.y) + bf16tof(tzl.y);
  float sm0 = bf16tof(smh.x) + bf16tof(sml.x);
  float sm1 = bf16tof(smh.y) + bf16tof(sml.y);
  float z0 = sigmoidf_(cz.x + tz0);
  float z1 = sigmoidf_(cz.y + tz1);
  float p0 = tanhf(ch.x + tv.x);
  float p1 = tanhf(ch.y + tv.y);
  float v0 = (1.f - z0) * sm0 + z0 * p0;
  float v1 = (1.f - z1) * sm1 + z1 * p1;
  if (m == 0) { v0 = 0.f; v1 = 0.f; }
  short2 h2, l2;
  bf16split(v0, h2.x, l2.x); bf16split(v1, h2.y, l2.y);
  *(short2*)&hP[oP] = h2; *(short2*)&hP[oP + 32] = l2;
}

// Acat packed [n][SPP2]: cols 0-449 = emb, 450-899 = sum h_nei, 900-959 = 0
__global__ void k_nodecat(const float* __restrict__ emb,
                          const int* __restrict__ fnode,
                          const short* __restrict__ hP,
                          const int* __restrict__ ng,
                          short* __restrict__ Apk) {
  int n = blockIdx.x, t = threadIdx.x, j = t * 2;
  if (j < H) {
    float2 v = *(const float2*)&emb[(size_t)fnode[n] * H + j];
    short2 h2, l2;
    bf16split(v.x, h2.x, l2.x); bf16split(v.y, h2.y, l2.y);
    size_t o = ppix(n, j, SPP2);
    *(short2*)&Apk[o] = h2; *(short2*)&Apk[o + 32] = l2;

    const int* e = ng + (size_t)n * KN;
    float s0 = 0.f, s1 = 0.f;
#pragma unroll
    for (int k = 0; k < KN; ++k) {
      size_t oP = ppix(e[k], j, SPP1);
      short2 ph = *(const short2*)&hP[oP];
      short2 pl = *(const short2*)&hP[oP + 32];
      s0 += bf16tof(ph.x) + bf16tof(pl.x);
      s1 += bf16tof(ph.y) + bf16tof(pl.y);
    }
    bf16split(s0, h2.x, l2.x); bf16split(s1, h2.y, l2.y);
    o = ppix(n, 450 + j, SPP2);   // 450+j even -> slot pair within one chunk
    *(short2*)&Apk[o] = h2; *(short2*)&Apk[o + 32] = l2;
  }
  if (t < 30) {   // zero cols [900,960)
    int c = 900 + t * 2;
    short2 z2; z2.x = 0; z2.y = 0;
    size_t o = ppix(n, c, SPP2);
    *(short2*)&Apk[o] = z2; *(short2*)&Apk[o + 32] = z2;
  }
}

// ---------------- launch ----------------

extern "C" void kernel_launch(void* const* d_in, const int* in_sizes, int n_in,
                              void* d_out, int out_size, void* d_ws, size_t ws_size,
                              hipStream_t stream) {
  (void)in_sizes; (void)n_in; (void)out_size; (void)ws_size;

  const int*   fnode      = (const int*)d_in[0];
  const int*   fmess      = (const int*)d_in[1];
  const int*   node_graph = (const int*)d_in[2];
  const int*   mess_graph = (const int*)d_in[3];
  const float* emb        = (const float*)d_in[4];
  const float* Wz         = (const float*)d_in[5];
  const float* bz         = (const float*)d_in[6];
  const float* Wr         = (const float*)d_in[7];
  const float* Ur         = (const float*)d_in[8];
  const float* bu         = (const float*)d_in[9];
  const float* Wh         = (const float*)d_in[10];
  const float* bh         = (const float*)d_in[11];
  const float* Wo         = (const float*)d_in[12];
  const float* bo         = (const float*)d_in[13];

  // ---- workspace: 3 packed planes + CH + g + r1b = 125.3 MB ----
  short* P   = (short*)d_ws;
  short* hP  = P;                     // h packed
  short* shP = P + 1 * PPSZ;          // sum_h packed (later Acat @ SPP2)
  short* ghP = P + 2 * PPSZ;          // sum_gh packed (also fmess_e packed)
  float* CH  = (float*)(P + 3 * PPSZ);        // [M][912]: c_z | c_h
  float* g   = CH + (size_t)NMESS * LDCH;     // [M][450] f32: Ur out / t_h
  short* r1b = (short*)(g + (size_t)NMESS * H); // [M][480] bf16

  // ---- d_out messages region (8.7 of 18.4 MB) ----
  char*  scr  = (char*)d_out + (size_t)NNODE * H * 4;   // 16B-aligned
  short* BtI  = (short*)scr;                    // [1408][960] packed (WzT|WhT)
  short* BtR  = BtI  + (size_t)1408 * SPP1;     // [512][960] Wr
  short* BtUr = BtR  + (size_t)512 * SPP1;      // [512][960] Ur
  short* BtZ  = BtUr + (size_t)512 * SPP1;      // [512][960] Wz bottom
  short* BtHH = BtZ  + (size_t)512 * SPP1;      // [512][960] Wh bottom
  short* BtO  = BtHH + (size_t)512 * SPP1;      // [512][1920] Wo
  float* biasI = (float*)(BtO + (size_t)512 * SPP2);    // [912]
  int*   idxM  = (int*)(biasI + LDCH);

  // zero packed planes (pad rows/cols + h0 = 0) and scratch region
  hipMemsetAsync(P, 0, 3 * PPSZ * sizeof(short), stream);
  hipMemsetAsync(scr, 0, (size_t)NMESS * H * sizeof(float), stream);

  k_build_idx<<<(NMESS + 255) / 256, 256, 0, stream>>>(fnode, fmess, idxM);

  // packed weight prep
  dim3 gT(KP / 32, 16), gT2(KP2 / 32, 16);
  k_wT<<<gT,  256, 0, stream>>>(Wz,                  H, BtI,               KP,  512);
  k_wT<<<gT,  256, 0, stream>>>(Wh,                  H, BtI + 450 * SPP1,  KP,  512);
  k_wT<<<gT,  256, 0, stream>>>(Wr,                  H, BtR,               KP,  512);
  k_wT<<<gT,  256, 0, stream>>>(Ur,                  H, BtUr,              KP,  512);
  k_wT<<<gT,  256, 0, stream>>>(Wz + (size_t)H * H,  H, BtZ,               KP,  512);
  k_wT<<<gT,  256, 0, stream>>>(Wh + (size_t)H * H,  H, BtHH,              KP,  512);
  k_wT<<<gT2, 256, 0, stream>>>(Wo,                 H2, BtO,               KP2, 512);
  k_biascat<<<4, 256, 0, stream>>>(bz, bh, biasI);

  // fmess_e packed into ghP
  k_embsplit<<<NMESS, 256, 0, stream>>>(emb, idxM, ghP);

  // invariant GEMMs: CH(c_z|c_h) f32 and r1b single-bf16
  dim3 gI1(15, MPAD / BM);   // N=900
  gemm4<0><<<gI1, 256, 0, stream>>>(ghP, KP, BtI, biasI, CH, LDCH, NMESS, H2);
  dim3 gI2(8, MPAD / BM);    // N=450
  gemm4_r<<<gI2, 256, 0, stream>>>(ghP, BtR, bu, r1b, NMESS, H);

  dim3 gB(8, MPAD / BM);     // (8, 162)
  dim3 gP(8, MPAD / BM, 2);  // grouped t_h + t_z
  for (int d = 0; d < 8; ++d) {
    // g = h @ Ur (f32, no bias)
    gemm4<0><<<gB, 256, 0, stream>>>(hP, KP, BtUr, nullptr, g, H, NMESS, H);
    // sum_h & sum_gh packed in one pass
    k_gather2<<<NMESS, 256, 0, stream>>>(hP, g, r1b, mess_graph, shP, ghP);
    // t_h = ghP@WhB -> g (dead)  ||  t_z = shP@WzB -> hP (old h dead)
    gemm4_pair<<<gP, 256, 0, stream>>>(ghP, BtHH, g, shP, BtZ, hP);
    // combine in place (tz in hP -> h)
    k_combine<<<NMESS, 256, 0, stream>>>(CH, g, shP, hP);
  }

  // Acat packed (SPP2) then output GEMM with relu
  k_nodecat<<<NNODE, 256, 0, stream>>>(emb, fnode, hP, node_graph, shP);
  dim3 gF(8, NNODE / BM);    // (8, 80)
  gemm4<1><<<gF, 256, 0, stream>>>(shP, KP2, BtO, bo, (float*)d_out, H, NNODE, H);

  // messages output = zeros (wipes idx + weights) — AFTER final GEMM
  hipMemsetAsync((float*)d_out + (size_t)NNODE * H, 0, (size_t)NMESS * H * sizeof(float), stream);
}

// Round 11
// 902.823 us; speedup vs baseline: 1.7044x; 1.1564x over previous
//
#include <hip/hip_runtime.h>
#include <cstdint>
#include <cstddef>

#define H 450
#define H2 900
#define KP 480
#define KP2 960
#define NMESS 10241
#define NNODE 5120
#define MPAD 10368                 // 162 * 64
#define SPP1 960                   // packed row stride (shorts) for Kpad=480
#define SPP2 1920                  // for Kpad=960
#define PPSZ ((size_t)MPAD * SPP1) // packed plane size in shorts
#define KM 5
#define KN 6
#define LDCH 960                   // CH row stride (bf16): c_z | c_h

typedef __attribute__((ext_vector_type(8))) short short8;   // 8 bf16
typedef __attribute__((ext_vector_type(4))) float f32x4;

__device__ __forceinline__ short bf16rne(float f) {
  union { float f; unsigned u; } x; x.f = f;
  unsigned u = x.u;
  u += 0x7FFF + ((u >> 16) & 1);
  return (short)(u >> 16);
}
__device__ __forceinline__ float bf16tof(short s) {
  union { float f; unsigned u; } x;
  x.u = ((unsigned)(unsigned short)s) << 16;
  return x.f;
}
__device__ __forceinline__ void bf16split(float v, short& hi, short& lo) {
  hi = bf16rne(v);
  lo = bf16rne(v - bf16tof(hi));
}
__device__ __forceinline__ float sigmoidf_(float x) {
  return 1.f / (1.f + __expf(-x));
}

// packed element offset: hi at PPIX, lo at PPIX+32
__device__ __forceinline__ size_t ppix(int row, int k, int spp) {
  return (size_t)row * spp + ((k >> 5) << 6) + (k & 31);
}

// direct global->LDS 16B DMA (LDS dest: wave-uniform base + lane*16)
__device__ __forceinline__ void gll16(const short* g, short* l) {
  __builtin_amdgcn_global_load_lds(
      (const __attribute__((address_space(1))) void*)g,
      (__attribute__((address_space(3))) void*)l, 16, 0, 0);
}

// ---------------- split-bf16 MFMA GEMM: packed planes ----------------
// A,B packed [row][k-chunk][hi*32|lo*32] bf16. 256 thr (4 waves, 32x32 wave
// tiles), BK=32, 2-buf 32 KB LDS -> 5 blocks/CU. gload_lds staging: one
// contiguous 128B run per row per chunk; source slot = (lane&7)^(row&7),
// read-side XOR matches. XCD-chunked block swizzle.
#define BM 64
#define BN 64
#define BK 32

struct SmemT { short As[2][64][64]; short Bs[2][64][64]; };   // 32 KB

__device__ __forceinline__ void xcd_swz(int gx, int gy, int& bm, int& bn) {
  const int nwg = gx * gy;
  int lid = blockIdx.y * gx + blockIdx.x;
  const int q = nwg >> 3, r = nwg & 7;
  const int xcd = lid & 7, seq = lid >> 3;
  int sid = (xcd < r) ? (xcd * (q + 1) + seq)
                      : (r * (q + 1) + (xcd - r) * q + seq);
  bm = (sid / gx) * BM;
  bn = (sid % gx) * BN;
}

// OUT: 0 = f32 C (+bias, opt relu)
//      1 = packed split bf16 planes (Cs, stride SPP1)
//      3 = single bf16 (Cs, stride ldc), +bias
template<int ACT, int OUT>
__device__ __forceinline__ void gemm_core(
    SmemT& sm, const short* __restrict__ Apk, int Kpad,
    const short* __restrict__ Bpk,
    const float* __restrict__ bias,
    float* C, int ldc, short* Cs,
    int M, int N, int bm, int bn)
{
  const int tid  = threadIdx.x;
  const int lane = tid & 63;
  const int wid  = tid >> 6;          // 0..3
  const int wm   = (wid >> 1) * 32;
  const int wn   = (wid & 1) * 32;
  const int l15  = lane & 15;
  const int s8   = (lane >> 4) * 8;   // k sub-offset in halves
  const int rr0  = (lane >> 4) * 4;
  const int spp  = Kpad * 2;

  // staging: unified 128 rows (0-63 = A, 64-127 = B); wave wid -> rows 32w..32w+31
  const int lr = lane >> 3;
  const int sl = lane & 7;
  const int t0 = sl ^ lr;             // packed slot (0-3 hi, 4-7 lo)
  const short* src[4];
#pragma unroll
  for (int qq = 0; qq < 4; ++qq) {
    const int rrow = wid * 32 + qq * 8 + lr;
    const bool isA = rrow < 64;
    const int grow = isA ? (bm + rrow) : (bn + rrow - 64);
    src[qq] = (isA ? Apk : Bpk) + (size_t)grow * spp + t0 * 8;
  }
  const int nk = Kpad / BK;

  f32x4 acc[2][2];
#pragma unroll
  for (int i = 0; i < 2; ++i)
#pragma unroll
    for (int j = 0; j < 2; ++j)
#pragma unroll
      for (int t = 0; t < 4; ++t) acc[i][j][t] = 0.f;

  auto STAGE = [&](int b, int koff) {
#pragma unroll
    for (int qq = 0; qq < 4; ++qq) {
      const int r0 = wid * 32 + qq * 8;
      short* d = (r0 < 64) ? &sm.As[b][r0][0] : &sm.Bs[b][r0 - 64][0];
      gll16(src[qq] + koff, d);
    }
  };

  STAGE(0, 0);
  __syncthreads();
  int cur = 0;
  for (int t = 0; t < nk; ++t) {
    if (t + 1 < nk) STAGE(cur ^ 1, (t + 1) * 64);
    short8 ah[2], al[2], bh[2], bl[2];
#pragma unroll
    for (int i = 0; i < 2; ++i) {
      const int rA = wm + i*16 + l15;
      const int xr = (rA & 7) << 3;
      ah[i] = *(const short8*)&sm.As[cur][rA][(s8)      ^ xr];
      al[i] = *(const short8*)&sm.As[cur][rA][(s8 + 32) ^ xr];
    }
#pragma unroll
    for (int j = 0; j < 2; ++j) {
      const int rB = wn + j*16 + l15;
      const int xr = (rB & 7) << 3;
      bh[j] = *(const short8*)&sm.Bs[cur][rB][(s8)      ^ xr];
      bl[j] = *(const short8*)&sm.Bs[cur][rB][(s8 + 32) ^ xr];
    }
    __builtin_amdgcn_s_setprio(1);
#pragma unroll
    for (int j = 0; j < 2; ++j)
#pragma unroll
      for (int i = 0; i < 2; ++i) {
        acc[i][j] = __builtin_amdgcn_mfma_f32_16x16x32_bf16(ah[i], bh[j], acc[i][j], 0, 0, 0);
        acc[i][j] = __builtin_amdgcn_mfma_f32_16x16x32_bf16(al[i], bh[j], acc[i][j], 0, 0, 0);
        acc[i][j] = __builtin_amdgcn_mfma_f32_16x16x32_bf16(ah[i], bl[j], acc[i][j], 0, 0, 0);
      }
    __builtin_amdgcn_s_setprio(0);
    __syncthreads();   // drains next-tile gload_lds + read/write order
    cur ^= 1;
  }

#pragma unroll
  for (int j = 0; j < 2; ++j) {
    int col = bn + wn + j*16 + l15;
    if (col >= N) continue;
    float bv = ((OUT == 0 || OUT == 3) && bias) ? bias[col] : 0.f;
#pragma unroll
    for (int i = 0; i < 2; ++i) {
      int row0 = bm + wm + i*16 + rr0;
#pragma unroll
      for (int rr = 0; rr < 4; ++rr) {
        int row = row0 + rr;
        if (row >= M) continue;
        float v = acc[i][j][rr] + bv;
        if (OUT == 0) {
          if (ACT == 1) v = fmaxf(v, 0.f);
          C[(size_t)row * ldc + col] = v;
        } else if (OUT == 1) {
          short hi, lo; bf16split(v, hi, lo);
          size_t o = ppix(row, col, SPP1);
          Cs[o] = hi; Cs[o + 32] = lo;
        } else {  // OUT == 3: single bf16, stride ldc
          Cs[(size_t)row * ldc + col] = bf16rne(v);
        }
      }
    }
  }
}

template<int ACT>
__global__ __launch_bounds__(256, 5)
void gemm4(const short* __restrict__ Apk, int Kpad,
           const short* __restrict__ Bpk,
           const float* __restrict__ bias,
           float* C, int ldc, int M, int N)
{
  __shared__ SmemT sm;
  int bm, bn; xcd_swz(gridDim.x, gridDim.y, bm, bn);
  gemm_core<ACT, 0>(sm, Apk, Kpad, Bpk, bias, C, ldc, nullptr, M, N, bm, bn);
}

// single-bf16 output GEMM (CH, r1b)
__global__ __launch_bounds__(256, 5)
void gemm4_b(const short* __restrict__ Apk, int Kpad,
             const short* __restrict__ Bpk,
             const float* __restrict__ bias,
             short* Cs, int ldcs, int M, int N)
{
  __shared__ SmemT sm;
  int bm, bn; xcd_swz(gridDim.x, gridDim.y, bm, bn);
  gemm_core<0, 3>(sm, Apk, Kpad, Bpk, bias, nullptr, ldcs, Cs, M, N, bm, bn);
}

// grouped: z=0: t_h = ghP@WhB -> g (f32); z=1: t_z = shP@WzB -> hP (packed)
__global__ __launch_bounds__(256, 5)
void gemm4_pair(const short* __restrict__ A0, const short* __restrict__ B0,
                float* C0,
                const short* __restrict__ A1, const short* __restrict__ B1,
                short* C1)
{
  __shared__ SmemT sm;
  int bm, bn; xcd_swz(gridDim.x, gridDim.y, bm, bn);
  if (blockIdx.z == 0)
    gemm_core<0, 0>(sm, A0, KP, B0, nullptr, C0, H, nullptr, NMESS, H, bm, bn);
  else
    gemm_core<0, 1>(sm, A1, KP, B1, nullptr, nullptr, 0, C1, NMESS, H, bm, bn);
}

// ---------------- weight transpose + packed bf16 hi/lo split ----------------
// Bt packed [c][chunk][hi|lo], c = column of original W; c < rmax written
__global__ __launch_bounds__(256)
void k_wT(const float* __restrict__ W, int Kreal,
          short* __restrict__ Bt, int Kpad, int rmax) {
  __shared__ float T[32][33];
  const int tx = threadIdx.x & 31;
  const int ty = threadIdx.x >> 5;
  const int k0 = blockIdx.x * 32;
  const int c0 = blockIdx.y * 32;
  const int spp = Kpad * 2;
#pragma unroll
  for (int i = 0; i < 4; ++i) {
    int k = k0 + ty + i*8, c = c0 + tx;
    T[ty + i*8][tx] = (k < Kreal && c < H) ? W[(size_t)k * H + c] : 0.f;
  }
  __syncthreads();
#pragma unroll
  for (int i = 0; i < 4; ++i) {
    int c = c0 + ty + i*8, k = k0 + tx;
    if (k < Kpad && c < rmax) {
      short hi, lo;
      bf16split(T[tx][ty + i*8], hi, lo);
      size_t o = ppix(c, k, spp);
      Bt[o] = hi; Bt[o + 32] = lo;
    }
  }
}

__global__ void k_biascat(const float* __restrict__ bz, const float* __restrict__ bh,
                          float* __restrict__ biasI) {
  int c = blockIdx.x * blockDim.x + threadIdx.x;
  if (c >= 900) return;
  biasI[c] = (c < 450) ? bz[c] : bh[c - 450];
}

// ---------------- elementwise / gather kernels ----------------

__global__ void k_build_idx(const int* __restrict__ fnode,
                            const int* __restrict__ fmess,
                            int* __restrict__ idxM) {
  int m = blockIdx.x * blockDim.x + threadIdx.x;
  if (m < NMESS) idxM[m] = fnode[fmess[m]];
}

__global__ void k_embsplit(const float* __restrict__ emb,
                           const int* __restrict__ idxM,
                           short* __restrict__ eP) {
  int m = blockIdx.x, j = threadIdx.x * 2;
  if (j >= KP) return;
  size_t o = ppix(m, j, SPP1);
  if (j < H) {
    float2 v = *(const float2*)&emb[(size_t)idxM[m] * H + j];
    short2 h2, l2;
    bf16split(v.x, h2.x, l2.x); bf16split(v.y, h2.y, l2.y);
    *(short2*)&eP[o] = h2; *(short2*)&eP[o + 32] = l2;
  } else {                      // K-tail cols [450,480) must be 0
    short2 z2; z2.x = 0; z2.y = 0;
    *(short2*)&eP[o] = z2; *(short2*)&eP[o + 32] = z2;
  }
}

// step 0: h1 = mask * sigmoid(c_z) * tanh(c_h)   (sum_h = t_z = t_h = 0)
__global__ void k_h1(const short* __restrict__ CHb, short* __restrict__ hP) {
  int m = blockIdx.x, j = threadIdx.x * 2;
  if (j >= KP) return;
  size_t oP = ppix(m, j, SPP1);
  if (j < H) {
    size_t oc = (size_t)m * LDCH + j;
    short2 cz2 = *(const short2*)&CHb[oc];
    short2 ch2 = *(const short2*)&CHb[oc + 450];
    float v0 = sigmoidf_(bf16tof(cz2.x)) * tanhf(bf16tof(ch2.x));
    float v1 = sigmoidf_(bf16tof(cz2.y)) * tanhf(bf16tof(ch2.y));
    if (m == 0) { v0 = 0.f; v1 = 0.f; }
    short2 h2, l2;
    bf16split(v0, h2.x, l2.x); bf16split(v1, h2.y, l2.y);
    *(short2*)&hP[oP] = h2; *(short2*)&hP[oP + 32] = l2;
  } else {
    short2 z2; z2.x = 0; z2.y = 0;
    *(short2*)&hP[oP] = z2; *(short2*)&hP[oP + 32] = z2;
  }
}

// one pass over neighbors: sum_h + sum_gh packed planes
__global__ void k_gather2(const short* __restrict__ hP,
                          const float* __restrict__ g,
                          const short* __restrict__ r1b,   // [M][480] bf16
                          const int* __restrict__ mg,
                          short* __restrict__ shP, short* __restrict__ ghP) {
  int m = blockIdx.x, j = threadIdx.x * 2;
  if (j >= KP) return;
  size_t o = ppix(m, j, SPP1);
  if (j >= H) {                 // K-tail zeros
    short2 z2; z2.x = 0; z2.y = 0;
    *(short2*)&shP[o] = z2; *(short2*)&shP[o + 32] = z2;
    *(short2*)&ghP[o] = z2; *(short2*)&ghP[o + 32] = z2;
    return;
  }
  const int* e = mg + (size_t)m * KM;
  short2 rb2 = *(const short2*)&r1b[(size_t)m * 480 + j];
  float rb0 = bf16tof(rb2.x), rb1 = bf16tof(rb2.y);
  float s0 = 0.f, s1 = 0.f, t0 = 0.f, t1 = 0.f;
#pragma unroll
  for (int k = 0; k < KM; ++k) {
    int ek = e[k];
    size_t oP = ppix(ek, j, SPP1);
    float2 gv = *(const float2*)&g[(size_t)ek * H + j];
    short2 ph = *(const short2*)&hP[oP];
    short2 pl = *(const short2*)&hP[oP + 32];
    float h0 = bf16tof(ph.x) + bf16tof(pl.x);
    float h1 = bf16tof(ph.y) + bf16tof(pl.y);
    s0 += h0;                          s1 += h1;
    t0 += sigmoidf_(rb0 + gv.x) * h0;  t1 += sigmoidf_(rb1 + gv.y) * h1;
  }
  short2 h2, l2;
  bf16split(s0, h2.x, l2.x); bf16split(s1, h2.y, l2.y);
  *(short2*)&shP[o] = h2; *(short2*)&shP[o + 32] = l2;
  bf16split(t0, h2.x, l2.x); bf16split(t1, h2.y, l2.y);
  *(short2*)&ghP[o] = h2; *(short2*)&ghP[o + 32] = l2;
}

// h = mask*((1-z)*sum_h + z*tanh(c_h+th)); tz read from hP, overwritten in place
__global__ void k_combine(const short* __restrict__ CHb,   // [M][960] bf16: c_z|c_h
                          const float* __restrict__ th,    // [M][450] f32 t_h
                          const short* __restrict__ shP,
                          short* hP) {
  int m = blockIdx.x, j = threadIdx.x * 2;
  if (j >= KP) return;
  size_t oP = ppix(m, j, SPP1);
  if (j >= H) {                 // K-tail zeros
    short2 z2; z2.x = 0; z2.y = 0;
    *(short2*)&hP[oP] = z2; *(short2*)&hP[oP + 32] = z2;
    return;
  }
  size_t oc = (size_t)m * LDCH + j;
  size_t og = (size_t)m * H + j;
  short2 cz2 = *(const short2*)&CHb[oc];
  short2 ch2 = *(const short2*)&CHb[oc + 450];
  float2 tv  = *(const float2*)&th[og];
  short2 tzh = *(const short2*)&hP[oP];
  short2 tzl = *(const short2*)&hP[oP + 32];
  short2 smh = *(const short2*)&shP[oP];
  short2 sml = *(const short2*)&shP[oP + 32];
  float tz0 = bf16tof(tzh.x) + bf16tof(tzl.x);
  float tz1 = bf16tof(tzh.y) + bf16tof(tzl.y);
  float sm0 = bf16tof(smh.x) + bf16tof(sml.x);
  float sm1 = bf16tof(smh.y) + bf16tof(sml.y);
  float z0 = sigmoidf_(bf16tof(cz2.x) + tz0);
  float z1 = sigmoidf_(bf16tof(cz2.y) + tz1);
  float p0 = tanhf(bf16tof(ch2.x) + tv.x);
  float p1 = tanhf(bf16tof(ch2.y) + tv.y);
  float v0 = (1.f - z0) * sm0 + z0 * p0;
  float v1 = (1.f - z1) * sm1 + z1 * p1;
  if (m == 0) { v0 = 0.f; v1 = 0.f; }
  short2 h2, l2;
  bf16split(v0, h2.x, l2.x); bf16split(v1, h2.y, l2.y);
  *(short2*)&hP[oP] = h2; *(short2*)&hP[oP + 32] = l2;
}

// Acat packed [n][SPP2]: cols 0-449 = emb, 450-899 = sum h_nei, 900-959 = 0
__global__ void k_nodecat(const float* __restrict__ emb,
                          const int* __restrict__ fnode,
                          const short* __restrict__ hP,
                          const int* __restrict__ ng,
                          short* __restrict__ Apk) {
  int n = blockIdx.x, t = threadIdx.x, j = t * 2;
  if (j < H) {
    float2 v = *(const float2*)&emb[(size_t)fnode[n] * H + j];
    short2 h2, l2;
    bf16split(v.x, h2.x, l2.x); bf16split(v.y, h2.y, l2.y);
    size_t o = ppix(n, j, SPP2);
    *(short2*)&Apk[o] = h2; *(short2*)&Apk[o + 32] = l2;

    const int* e = ng + (size_t)n * KN;
    float s0 = 0.f, s1 = 0.f;
#pragma unroll
    for (int k = 0; k < KN; ++k) {
      size_t oP = ppix(e[k], j, SPP1);
      short2 ph = *(const short2*)&hP[oP];
      short2 pl = *(const short2*)&hP[oP + 32];
      s0 += bf16tof(ph.x) + bf16tof(pl.x);
      s1 += bf16tof(ph.y) + bf16tof(pl.y);
    }
    bf16split(s0, h2.x, l2.x); bf16split(s1, h2.y, l2.y);
    o = ppix(n, 450 + j, SPP2);
    *(short2*)&Apk[o] = h2; *(short2*)&Apk[o + 32] = l2;
  }
  if (t < 30) {   // zero cols [900,960)
    int c = 900 + t * 2;
    short2 z2; z2.x = 0; z2.y = 0;
    size_t o = ppix(n, c, SPP2);
    *(short2*)&Apk[o] = z2; *(short2*)&Apk[o + 32] = z2;
  }
}

// ---------------- launch ----------------

extern "C" void kernel_launch(void* const* d_in, const int* in_sizes, int n_in,
                              void* d_out, int out_size, void* d_ws, size_t ws_size,
                              hipStream_t stream) {
  (void)in_sizes; (void)n_in; (void)out_size; (void)ws_size;

  const int*   fnode      = (const int*)d_in[0];
  const int*   fmess      = (const int*)d_in[1];
  const int*   node_graph = (const int*)d_in[2];
  const int*   mess_graph = (const int*)d_in[3];
  const float* emb        = (const float*)d_in[4];
  const float* Wz         = (const float*)d_in[5];
  const float* bz         = (const float*)d_in[6];
  const float* Wr         = (const float*)d_in[7];
  const float* Ur         = (const float*)d_in[8];
  const float* bu         = (const float*)d_in[9];
  const float* Wh         = (const float*)d_in[10];
  const float* bh         = (const float*)d_in[11];
  const float* Wo         = (const float*)d_in[12];
  const float* bo         = (const float*)d_in[13];

  // ---- workspace: 3 packed planes + CHb + g + r1b ≈ 107.6 MB ----
  short* P   = (short*)d_ws;
  short* hP  = P;                     // h packed
  short* shP = P + 1 * PPSZ;          // sum_h packed (later Acat @ SPP2)
  short* ghP = P + 2 * PPSZ;          // sum_gh packed (also fmess_e packed)
  short* CHb = P + 3 * PPSZ;                    // [M][960] bf16: c_z | c_h
  float* g   = (float*)(CHb + (size_t)NMESS * LDCH + 64); // [M][450] f32
  short* r1b = (short*)(g + (size_t)NMESS * H);           // [M][480] bf16

  // ---- d_out messages region: packed weights (~8.7 of 18.4 MB) ----
  char*  scr  = (char*)d_out + (size_t)NNODE * H * 4;   // 16B-aligned
  short* BtI  = (short*)scr;                    // [1408][960] packed (WzT|WhT)
  short* BtR  = BtI  + (size_t)1408 * SPP1;     // [512][960] Wr
  short* BtUr = BtR  + (size_t)512 * SPP1;      // [512][960] Ur
  short* BtZ  = BtUr + (size_t)512 * SPP1;      // [512][960] Wz bottom
  short* BtHH = BtZ  + (size_t)512 * SPP1;      // [512][960] Wh bottom
  short* BtO  = BtHH + (size_t)512 * SPP1;      // [512][1920] Wo
  float* biasI = (float*)(BtO + (size_t)512 * SPP2);    // [900]
  int*   idxM  = (int*)(biasI + 912);

  k_build_idx<<<(NMESS + 255) / 256, 256, 0, stream>>>(fnode, fmess, idxM);

  // packed weight prep (fully overwrites every region read later)
  dim3 gT(KP / 32, 16), gT2(KP2 / 32, 16);
  k_wT<<<gT,  256, 0, stream>>>(Wz,                  H, BtI,               KP,  512);
  k_wT<<<gT,  256, 0, stream>>>(Wh,                  H, BtI + 450 * SPP1,  KP,  512);
  k_wT<<<gT,  256, 0, stream>>>(Wr,                  H, BtR,               KP,  512);
  k_wT<<<gT,  256, 0, stream>>>(Ur,                  H, BtUr,              KP,  512);
  k_wT<<<gT,  256, 0, stream>>>(Wz + (size_t)H * H,  H, BtZ,               KP,  512);
  k_wT<<<gT,  256, 0, stream>>>(Wh + (size_t)H * H,  H, BtHH,              KP,  512);
  k_wT<<<gT2, 256, 0, stream>>>(Wo,                 H2, BtO,               KP2, 512);
  k_biascat<<<4, 256, 0, stream>>>(bz, bh, biasI);

  // fmess_e packed into ghP (writes K-tail zeros inline)
  k_embsplit<<<NMESS, 256, 0, stream>>>(emb, idxM, ghP);

  // invariant GEMMs: CHb (c_z|c_h, bf16) and r1b (bf16)
  dim3 gI1(15, MPAD / BM);   // N=900
  gemm4_b<<<gI1, 256, 0, stream>>>(ghP, KP, BtI, biasI, CHb, LDCH, NMESS, H2);
  dim3 gI2(8, MPAD / BM);    // N=450
  gemm4_b<<<gI2, 256, 0, stream>>>(ghP, KP, BtR, bu, r1b, 480, NMESS, H);

  // step 0 shortcut: h1 = mask * sigmoid(c_z) * tanh(c_h)
  k_h1<<<NMESS, 256, 0, stream>>>(CHb, hP);

  dim3 gB(8, MPAD / BM);     // (8, 162)
  dim3 gP(8, MPAD / BM, 2);  // grouped t_h + t_z
  for (int d = 1; d < 8; ++d) {
    // g = h @ Ur (f32, no bias)
    gemm4<0><<<gB, 256, 0, stream>>>(hP, KP, BtUr, nullptr, g, H, NMESS, H);
    // sum_h & sum_gh packed in one pass (K-tail zeros inline)
    k_gather2<<<NMESS, 256, 0, stream>>>(hP, g, r1b, mess_graph, shP, ghP);
    // t_h = ghP@WhB -> g (dead)  ||  t_z = shP@WzB -> hP (old h dead)
    gemm4_pair<<<gP, 256, 0, stream>>>(ghP, BtHH, g, shP, BtZ, hP);
    // combine in place (tz in hP -> h)
    k_combine<<<NMESS, 256, 0, stream>>>(CHb, g, shP, hP);
  }

  // Acat packed (SPP2) then output GEMM with relu
  k_nodecat<<<NNODE, 256, 0, stream>>>(emb, fnode, hP, node_graph, shP);
  dim3 gF(8, NNODE / BM);    // (8, 80)
  gemm4<1><<<gF, 256, 0, stream>>>(shP, KP2, BtO, bo, (float*)d_out, H, NNODE, H);

  // messages output = zeros (wipes idx + weights) — AFTER final GEMM
  hipMemsetAsync((float*)d_out + (size_t)NNODE * H, 0, (size_t)NMESS * H * sizeof(float), stream);
}